// Round 1
// baseline (284.564 us; speedup 1.0000x reference)
//
#include <hip/hip_runtime.h>
#include <hip/hip_bf16.h>

#define NN 20000
#define NE 320000
#define FDIM 32
#define YS 544      // 16 conv basis blocks * 32 + 32 fc cols

typedef __attribute__((ext_vector_type(8))) short short8;
typedef __attribute__((ext_vector_type(4))) float f32x4;

__device__ __forceinline__ unsigned short f2bf(float v) {
    // round-to-nearest-even f32 -> bf16 bits
    unsigned u = __float_as_uint(v);
    unsigned r = (u + 0x7fffu + ((u >> 16) & 1u)) >> 16;
    return (unsigned short)r;
}
__device__ __forceinline__ float bf2f(unsigned short s) {
    return __uint_as_float(((unsigned)s) << 16);
}

// ---- build combined weight matrix Wext[k=fin 0..31][col 0..543] bf16 per layer
__global__ __launch_bounds__(256) void prepw_kernel(const float* __restrict__ convW,
                                                    const float* __restrict__ fcW,
                                                    unsigned short* __restrict__ out) {
    int idx = blockIdx.x * 256 + threadIdx.x;       // 32*544 = 17408
    if (idx >= 32 * YS) return;
    int k = idx / YS, c = idx % YS;
    float v = (c < 512) ? convW[((c >> 5) * 32 + k) * 32 + (c & 31)]
                        : fcW[k * 32 + (c & 31)];
    out[idx] = f2bf(v);
}

// ---- CSR build: histogram
__global__ __launch_bounds__(256) void hist_kernel(const int* __restrict__ ei, int* __restrict__ counts) {
    int e = blockIdx.x * 256 + threadIdx.x;
    if (e < NE) atomicAdd(&counts[ei[e]], 1);
}

// ---- CSR build: single-block scan (20000 elems), writes row_start and cursor
__global__ __launch_bounds__(1024) void scan_kernel(const int* __restrict__ counts,
                                                    int* __restrict__ rowst,
                                                    int* __restrict__ cursor) {
    __shared__ int s[1024];
    int t = threadIdx.x;
    int carry = 0;
    if (t == 0) rowst[0] = 0;
    for (int base = 0; base < NN; base += 1024) {
        int idx = base + t;
        int v = (idx < NN) ? counts[idx] : 0;
        s[t] = v;
        __syncthreads();
        for (int off = 1; off < 1024; off <<= 1) {
            int add = (t >= off) ? s[t - off] : 0;
            __syncthreads();
            s[t] += add;
            __syncthreads();
        }
        int incl = s[t];
        if (idx < NN) { rowst[idx + 1] = carry + incl; cursor[idx] = carry + incl - v; }
        int tot = s[1023];
        __syncthreads();
        carry += tot;
    }
}

// ---- CSR fill + edge basis precompute (phi is layer-invariant)
__global__ __launch_bounds__(256) void fill_kernel(const int* __restrict__ ei,
                                                   const int* __restrict__ ej,
                                                   const float* __restrict__ attr,
                                                   int* __restrict__ cursor,
                                                   int* __restrict__ cols,
                                                   int* __restrict__ bidx,
                                                   float4* __restrict__ wph) {
    int e = blockIdx.x * 256 + threadIdx.x;
    if (e >= NE) return;
    int i = ei[e], j = ej[e];
    int p = atomicAdd(&cursor[i], 1);
    float2 a = ((const float2*)attr)[e];
    float d0 = fminf(fmaxf(a.x, -1.f), 1.f);
    float d1 = fminf(fmaxf(a.y, -1.f), 1.f);
    float tx = (d0 + 1.f) * 1.5f;
    float ty = (d1 + 1.f) * 1.5f;
    int ix = min(2, max(0, (int)floorf(tx)));
    int iy = min(2, max(0, (int)floorf(ty)));
    float ux = tx - (float)ix;
    float uy = ty - (float)iy;
    float m = (i != j) ? 1.f : 0.f;   // centerIgnore
    float4 w;
    w.x = (1.f - ux) * (1.f - uy) * m;   // (dx=0,dy=0)
    w.y = (1.f - ux) * uy * m;           // (dx=0,dy=1)
    w.z = ux * (1.f - uy) * m;           // (dx=1,dy=0)
    w.w = ux * uy * m;                   // (dx=1,dy=1)
    cols[p] = j;
    bidx[p] = ix * 4 + iy;
    wph[p] = w;
}

// ---- y[n][544] = bf16( (relu?)A[n][0..31] @ Wext ), one MFMA per 16x16 tile (K=32)
__global__ __launch_bounds__(256) void gemm_kernel(const float* __restrict__ A,
                                                   const unsigned short* __restrict__ Wl,
                                                   unsigned short* __restrict__ y,
                                                   int relu) {
    int wv = threadIdx.x >> 6, lane = threadIdx.x & 63;
    int ct = blockIdx.y * 4 + wv;
    if (ct >= 34) return;                 // 544/16 = 34 col tiles
    int c0 = ct * 16;
    int m0 = blockIdx.x * 16;             // 20000/16 = 1250 exact
    int row = lane & 15;
    int kb = (lane >> 4) * 8;
    const float* ar = A + (size_t)(m0 + row) * 32 + kb;
    short8 av, bv;
#pragma unroll
    for (int i = 0; i < 8; i++) {
        float v = ar[i];
        if (relu) v = fmaxf(v, 0.f);
        av[i] = (short)f2bf(v);
    }
    int col = c0 + (lane & 15);
#pragma unroll
    for (int i = 0; i < 8; i++)
        bv[i] = (short)Wl[(size_t)(kb + i) * YS + col];
    f32x4 acc = {0.f, 0.f, 0.f, 0.f};
    acc = __builtin_amdgcn_mfma_f32_16x16x32_bf16(av, bv, acc, 0, 0, 0);
#pragma unroll
    for (int r = 0; r < 4; r++) {
        int orow = m0 + (lane >> 4) * 4 + r;   // C/D: col=lane&15, row=(lane>>4)*4+r
        y[(size_t)orow * YS + col] = f2bf(acc[r]);
    }
}

// ---- per-node accumulation: one wave per node, lane=(dy, fout)
// mode: 0 = first layer (no residual), 1 = mid (residual), 2 = last (residual + scale -> d_out)
__global__ __launch_bounds__(256) void node_kernel(const unsigned short* __restrict__ y,
                                                   const float4* __restrict__ wph,
                                                   const int* __restrict__ cols,
                                                   const int* __restrict__ bidx,
                                                   const int* __restrict__ rowst,
                                                   const float* __restrict__ bias,
                                                   const float* __restrict__ ansin,
                                                   float* __restrict__ ansout,
                                                   int mode) {
    int node = blockIdx.x * 4 + (threadIdx.x >> 6);
    int lane = threadIdx.x & 63;
    int f = lane & 31;
    int dy = lane >> 5;
    int r0 = rowst[node], r1 = rowst[node + 1];
    float acc = 0.f;
    int j = 0, bb = 0;
    float4 w = {0.f, 0.f, 0.f, 0.f};
    if (r0 < r1) { j = cols[r0]; w = wph[r0]; bb = bidx[r0]; }
    for (int q = r0; q < r1; ++q) {
        int jc = j; float4 wc = w; int bbc = bb;
        if (q + 1 < r1) { j = cols[q + 1]; w = wph[q + 1]; bb = bidx[q + 1]; }  // prefetch meta
        const unsigned short* yr = y + (size_t)jc * YS + (bbc + dy) * 32 + f;
        float v0 = bf2f(yr[0]);     // block (bx0,   by0+dy)
        float v1 = bf2f(yr[128]);   // block (bx0+1, by0+dy)
        float wa = dy ? wc.y : wc.x;
        float wb = dy ? wc.w : wc.z;
        acc += wa * v0;
        acc += wb * v1;
    }
    acc += __shfl_xor(acc, 32);     // combine the two dy halves
    if (lane < 32) {
        float val = acc + bf2f(y[(size_t)node * YS + 512 + f]) + bias[f];
        if (mode) val += ansin[(size_t)node * 32 + f];
        if (mode == 2) val *= (1.f / 128.f);
        ansout[(size_t)node * 32 + f] = val;
    }
}

extern "C" void kernel_launch(void* const* d_in, const int* in_sizes, int n_in,
                              void* d_out, int out_size, void* d_ws, size_t ws_size,
                              hipStream_t stream) {
    const float* feat = (const float*)d_in[0];
    const int* ei = (const int*)d_in[1];
    const int* ej = (const int*)d_in[2];
    const float* attr = (const float*)d_in[3];
    const float *convW[4], *fcW[4], *fcB[4];
    if (n_in >= 16) {
        for (int l = 0; l < 4; l++) {
            convW[l] = (const float*)d_in[4 + l];
            fcW[l]   = (const float*)d_in[8 + l];
            fcB[l]   = (const float*)d_in[12 + l];
        }
    } else {
        // lists passed concatenated
        const float* cb = (const float*)d_in[4];
        const float* fb = (const float*)d_in[5];
        const float* bb = (const float*)d_in[6];
        for (int l = 0; l < 4; l++) {
            convW[l] = cb + (size_t)l * 16 * 32 * 32;
            fcW[l]   = fb + (size_t)l * 32 * 32;
            fcB[l]   = bb + (size_t)l * 32;
        }
    }

    // workspace bump allocator (256B aligned)
    char* p = (char*)d_ws;
    auto alloc = [&](size_t bytes) -> void* {
        void* r = (void*)p;
        p += (bytes + 255) & ~(size_t)255;
        return r;
    };
    unsigned short* wext = (unsigned short*)alloc(4 * 32 * YS * sizeof(unsigned short));
    float4* wph   = (float4*)alloc((size_t)NE * sizeof(float4));
    int* cols     = (int*)alloc((size_t)NE * sizeof(int));
    int* bidx     = (int*)alloc((size_t)NE * sizeof(int));
    int* counts   = (int*)alloc((size_t)NN * sizeof(int));
    int* cursor   = (int*)alloc((size_t)NN * sizeof(int));
    int* rowst    = (int*)alloc((size_t)(NN + 1) * sizeof(int));
    unsigned short* y = (unsigned short*)alloc((size_t)NN * YS * sizeof(unsigned short));
    float* ans    = (float*)alloc((size_t)NN * FDIM * sizeof(float));
    float* outf   = (float*)d_out;

    hipMemsetAsync(counts, 0, (size_t)NN * sizeof(int), stream);

    for (int l = 0; l < 4; l++)
        prepw_kernel<<<68, 256, 0, stream>>>(convW[l], fcW[l], wext + (size_t)l * 32 * YS);

    hist_kernel<<<(NE + 255) / 256, 256, 0, stream>>>(ei, counts);
    scan_kernel<<<1, 1024, 0, stream>>>(counts, rowst, cursor);
    fill_kernel<<<(NE + 255) / 256, 256, 0, stream>>>(ei, ej, attr, cursor, cols, bidx, wph);

    for (int l = 0; l < 4; l++) {
        const float* A = (l == 0) ? feat : ans;
        gemm_kernel<<<dim3(NN / 16, 9), 256, 0, stream>>>(A, wext + (size_t)l * 32 * YS, y, l > 0);
        int mode = (l == 0) ? 0 : ((l == 3) ? 2 : 1);
        float* dst = (l == 3) ? outf : ans;
        node_kernel<<<NN / 4, 256, 0, stream>>>(y, wph, cols, bidx, rowst, fcB[l],
                                                ans, dst, mode);
    }
}